// Round 6
// baseline (249.625 us; speedup 1.0000x reference)
//
#include <hip/hip_runtime.h>

using bf16x8 = __attribute__((ext_vector_type(8))) short;
using f32x4  = __attribute__((ext_vector_type(4))) float;
using f32x16 = __attribute__((ext_vector_type(16))) float;
using u32x2  = __attribute__((ext_vector_type(2))) unsigned int;

__device__ __forceinline__ unsigned short f2bf(float f) {
  unsigned int u = __float_as_uint(f);
  u = u + 0x7fffu + ((u >> 16) & 1u);   // round-to-nearest-even
  return (unsigned short)(u >> 16);
}

#if __has_builtin(__builtin_amdgcn_exp2f)
#define EXP2(x) __builtin_amdgcn_exp2f(x)
#else
#define EXP2(x) __expf((x) * 0.69314718056f)
#endif

// v_cvt_pk_bf16_f32: pack 2 f32 -> 2 bf16 (RTNE) in one instruction [T12]
__device__ __forceinline__ unsigned int cvt_pk_bf16(float lo, float hi) {
  unsigned int r;
  asm("v_cvt_pk_bf16_f32 %0, %1, %2" : "=v"(r) : "v"(lo), "v"(hi));
  return r;
}

#define GLL16(SRC, DST) __builtin_amdgcn_global_load_lds( \
    (const __attribute__((address_space(1))) unsigned int*)(SRC), \
    (__attribute__((address_space(3))) unsigned int*)(DST), 16, 0, 0)

// ---------------- converts ----------------
__global__ void cvt_x_kernel(const float* __restrict__ x, unsigned short* __restrict__ xb, int n4) {
  int i = blockIdx.x * blockDim.x + threadIdx.x;
  if (i >= n4) return;
  const float4 v = reinterpret_cast<const float4*>(x)[i];
  ushort2 o0 = { f2bf(v.x), f2bf(v.y) };
  ushort2 o1 = { f2bf(v.z), f2bf(v.w) };
  reinterpret_cast<ushort2*>(xb)[2 * i]     = o0;
  reinterpret_cast<ushort2*>(xb)[2 * i + 1] = o1;
}

// W (K x N) f32 row-major -> Wt (N x K) bf16 row-major. LDS-tiled, coalesced both sides.
__global__ __launch_bounds__(256) void cvt_wt_kernel(
    const float* __restrict__ W, unsigned short* __restrict__ Wt, int N, int K) {
  __shared__ float tile[32][33];
  const int n0 = blockIdx.x * 32, k0 = blockIdx.y * 32;
  const int tx = threadIdx.x & 31, ty = threadIdx.x >> 5;
  #pragma unroll
  for (int i = 0; i < 32; i += 8)
    tile[ty + i][tx] = W[(size_t)(k0 + ty + i) * N + n0 + tx];
  __syncthreads();
  #pragma unroll
  for (int i = 0; i < 32; i += 8)
    Wt[(size_t)(n0 + ty + i) * K + k0 + tx] = f2bf(tile[tx][ty + i]);
}

// ---------------- GEMM (m97 structure): C = A(M x K) @ Bt^T + bias ----------------
// MODE 0: fused QKV. N=1152. col<1024 -> Q bf16 (b,h,n,d) scaled by 0.125*log2e;
//         col in [1024,1088) -> K (b*n,64); col >= 1088 -> V^T (b,d,n).
// MODE 2: out0 = fp32 row-major (M x N).
template<int MODE>
__global__ __launch_bounds__(256) void gemm_kernel(
    const unsigned short* __restrict__ A, const unsigned short* __restrict__ Bt,
    const float* __restrict__ bias0, const float* __restrict__ bias1,
    const float* __restrict__ bias2,
    void* __restrict__ out0, void* __restrict__ out1, void* __restrict__ out2,
    int K, int N) {
  __shared__ __align__(16) unsigned short alds[2][128 * 32];
  __shared__ __align__(16) unsigned short blds[2][128 * 32];

  const int t    = threadIdx.x;
  const int lane = t & 63;
  const int wid  = t >> 6;
  const int lr = lane & 15, lg = lane >> 4;
  const int row0 = blockIdx.x * 128;
  const int col0 = blockIdx.y * 128;

  const size_t ldb = (size_t)K * 2;
  const char* Ag = (const char*)A  + (size_t)(row0 + (t >> 2)) * ldb + ((t & 3) << 4);
  const char* Bg = (const char*)Bt + (size_t)(col0 + (t >> 2)) * ldb + ((t & 3) << 4);
  char* adst = (char*)alds[0] + wid * 1024;
  char* bdst = (char*)blds[0] + wid * 1024;

  auto stage = [&](int buf, int k0) {
    const size_t kb = (size_t)k0 * 2;
    #pragma unroll
    for (int c = 0; c < 2; ++c) {
      GLL16(Ag + (size_t)c * 64 * ldb + kb, adst + buf * 8192 + c * 4096);
      GLL16(Bg + (size_t)c * 64 * ldb + kb, bdst + buf * 8192 + c * 4096);
    }
  };

  f32x4 acc[4][4];
  #pragma unroll
  for (int i = 0; i < 4; ++i)
    #pragma unroll
    for (int j = 0; j < 4; ++j)
      #pragma unroll
      for (int r = 0; r < 4; ++r) acc[i][j][r] = 0.f;

  stage(0, 0);
  __syncthreads();

  for (int step = 0; step < 32; ++step) {
    const int cur = step & 1;
    if (step < 31) stage(cur ^ 1, (step + 1) * 32);

    const char* ab = (const char*)alds[cur] + (wid >> 1) * 4096;
    const char* bb = (const char*)blds[cur] + (wid & 1) * 4096;
    bf16x8 am[4], bn[4];
    #pragma unroll
    for (int i = 0; i < 4; ++i)
      am[i] = *reinterpret_cast<const bf16x8*>(ab + (i * 16 + lr) * 64 + lg * 16);
    #pragma unroll
    for (int j = 0; j < 4; ++j)
      bn[j] = *reinterpret_cast<const bf16x8*>(bb + (j * 16 + lr) * 64 + lg * 16);
    #pragma unroll
    for (int i = 0; i < 4; ++i)
      #pragma unroll
      for (int j = 0; j < 4; ++j)
        acc[i][j] = __builtin_amdgcn_mfma_f32_16x16x32_bf16(am[i], bn[j], acc[i][j], 0, 0, 0);

    __syncthreads();
  }

  const int wrow0 = row0 + (wid >> 1) * 64;
  const int wcol0 = col0 + (wid & 1) * 64;
  #pragma unroll
  for (int i = 0; i < 4; ++i) {
    #pragma unroll
    for (int j = 0; j < 4; ++j) {
      const int col = wcol0 + j * 16 + lr;
      float bias;
      if constexpr (MODE == 0)
        bias = (col < 1024) ? bias0[col] : ((col < 1088) ? bias1[col - 1024] : bias2[col - 1088]);
      else
        bias = bias0[col];
      #pragma unroll
      for (int r = 0; r < 4; ++r) {
        const int row = wrow0 + i * 16 + lg * 4 + r;
        float v = acc[i][j][r] + bias;
        if constexpr (MODE == 0) {
          const int b = row >> 11, n = row & 2047;
          if (col < 1024) {
            v *= 0.180336880111f;  // 0.125 * log2(e): softmax scale + exp2 domain
            const int h = col >> 6, d = col & 63;
            ((unsigned short*)out0)[(((b * 16 + h) * 2048) + n) * 64 + d] = f2bf(v);
          } else if (col < 1088) {
            ((unsigned short*)out1)[row * 64 + (col - 1024)] = f2bf(v);      // K: (b*2048+n, d)
          } else {
            ((unsigned short*)out2)[(b * 64 + (col - 1088)) * 2048 + n] = f2bf(v); // Vt: (b,d,n)
          }
        } else {
          ((float*)out0)[(size_t)row * N + col] = v;
        }
      }
    }
  }
}

// ---------------- attention ----------------
// 8 waves x 32 q-rows, grid (8, 64). K: LDS dbuf via global_load_lds (XOR-swizzled).
// V: NOT staged — b128 global reads from L2-resident V^T (b,d,n).
// QK^T: 16x16x32 swapped (round-4-validated D-layout), no max subtraction (scores
// pre-scaled 0.125*log2e, bounded), exp2 + cvt_pk, P -> per-wave swizzled LDS.
// PV: 32x32x16, O^T = mfma(V-frag, P-frag): BOTH operands loaded positionally
// (lane (la,hi): keys 16*s16 + 8*hi + 0..7) so the HW input mapping cancels.
// lsum reduced once in epilogue (no per-tile cross-lane ops).
__global__ __launch_bounds__(512, 4) void attn_kernel(
    const unsigned short* __restrict__ Q,   // (bh, n, 64), pre-scaled by 0.125*log2e
    const unsigned short* __restrict__ Kb,  // (b, n, 64)
    const unsigned short* __restrict__ Vt,  // (b, 64, n)
    unsigned short* __restrict__ Ao) {      // (b, n, 1024)
  __shared__ __align__(16) unsigned short klds[2][64 * 64];   // 16 KB
  __shared__ __align__(16) unsigned short plds[8][32 * 64];   // 32 KB (per-wave 32q x 64k)

  const int lane = threadIdx.x & 63;
  const int wid  = threadIdx.x >> 6;
  const int lr = lane & 15, lg = lane >> 4;       // 16x16 indices (QK, P-write)
  const int la = lane & 31, hi = lane >> 5;       // 32x32 indices (PV, epilogue)
  const int swzK = (lr & 7) << 4;                 // swizzle for rows where row&7 == lr&7
  const int swzP = (la & 7) << 4;                 // swizzle for rows where row&7 == la&7
  const int bh = blockIdx.y, b = bh >> 4, h = bh & 15;
  const int q0 = blockIdx.x * 256 + wid * 32;

  const unsigned short* Qb = Q + (size_t)bh * 2048 * 64;
  const char* Kbase = (const char*)(Kb + (size_t)b * 2048 * 64);
  const unsigned short* Vg = Vt + (size_t)b * 64 * 2048;

  // K staging: wave w stages rows w*8..w*8+7 (1 KB per gload_lds), pre-swizzled source
  const int srow  = lane >> 3;
  const int schnk = (lane & 7) ^ (srow & 7);
  const int koff_lane = (wid * 8 + srow) * 128 + schnk * 16;
  char* kdst = (char*)klds[0] + wid * 1024;

  auto stage = [&](int buf, int kt) {
    GLL16(Kbase + (size_t)kt * 8192 + koff_lane, kdst + buf * 8192);
  };

  // Q B-frags (loop-invariant): col=q=lr, k = kc*32 + lg*8 + j
  bf16x8 qa[2][2];
  #pragma unroll
  for (int iq = 0; iq < 2; ++iq)
    #pragma unroll
    for (int kc = 0; kc < 2; ++kc)
      qa[iq][kc] = *reinterpret_cast<const bf16x8*>(
          &Qb[(q0 + iq * 16 + lr) * 64 + kc * 32 + lg * 8]);

  float lsum[2] = {0.f, 0.f};
  f32x16 o[2];
  #pragma unroll
  for (int dt = 0; dt < 2; ++dt)
    #pragma unroll
    for (int r = 0; r < 16; ++r) o[dt][r] = 0.f;

  stage(0, 0);
  __syncthreads();

  for (int kt = 0; kt < 32; ++kt) {
    const int cur = kt & 1;
    if (kt < 31) stage(cur ^ 1, kt + 1);   // prefetch next K tile

    const char* kb8 = (const char*)klds[cur];
    char* pw = (char*)plds[wid];

    // V prefetch (global, L2-resident): positional frags, row d = dt*32+la,
    // keys kt*64 + s16*16 + hi*8 + 0..7 (contiguous b128)
    bf16x8 vf[4][2];
    #pragma unroll
    for (int s16 = 0; s16 < 4; ++s16)
      #pragma unroll
      for (int dt = 0; dt < 2; ++dt)
        vf[s16][dt] = *reinterpret_cast<const bf16x8*>(
            &Vg[(size_t)(dt * 32 + la) * 2048 + kt * 64 + s16 * 16 + hi * 8]);

    // S^T = K @ Q^T (16x16x32): D row=key=lg*4+r, col=q=lr  [round-4-validated]
    f32x4 s[2][4];
    #pragma unroll
    for (int iq = 0; iq < 2; ++iq)
      #pragma unroll
      for (int ct = 0; ct < 4; ++ct)
        #pragma unroll
        for (int r = 0; r < 4; ++r) s[iq][ct][r] = 0.f;

    #pragma unroll
    for (int kc = 0; kc < 2; ++kc) {
      bf16x8 kf[4];
      #pragma unroll
      for (int ct = 0; ct < 4; ++ct)
        kf[ct] = *reinterpret_cast<const bf16x8*>(
            kb8 + ((ct * 16 + lr) << 7) + ((((kc << 2) + lg) << 4) ^ swzK));
      #pragma unroll
      for (int iq = 0; iq < 2; ++iq)
        #pragma unroll
        for (int ct = 0; ct < 4; ++ct)
          s[iq][ct] = __builtin_amdgcn_mfma_f32_16x16x32_bf16(kf[ct], qa[iq][kc], s[iq][ct], 0, 0, 0);
    }

    // P = exp2(S); pack bf16 pairs; write to per-wave swizzled P-LDS.
    // Lane (lr,lg), s[iq][ct][r]: q-row = iq*16+lr, key = ct*16 + lg*4 + r.
    // Write b64 at row*128 + ((ct*32 + lg*8) ^ ((row&7)<<4))  [conflict-free]
    #pragma unroll
    for (int iq = 0; iq < 2; ++iq) {
      const int rowb = (iq * 16 + lr) << 7;
      float ps = 0.f;
      #pragma unroll
      for (int ct = 0; ct < 4; ++ct) {
        const float p0 = EXP2(s[iq][ct][0]);
        const float p1 = EXP2(s[iq][ct][1]);
        const float p2 = EXP2(s[iq][ct][2]);
        const float p3 = EXP2(s[iq][ct][3]);
        ps += (p0 + p1) + (p2 + p3);
        u32x2 pk2;
        pk2[0] = cvt_pk_bf16(p0, p1);
        pk2[1] = cvt_pk_bf16(p2, p3);
        *(u32x2*)(pw + rowb + ((ct * 32 + lg * 8) ^ swzK)) = pk2;
      }
      lsum[iq] += ps;
    }

    // O^T += V^T @ P^T (32x32x16): A=V-frag (global), B=P-frag (LDS), both
    // positional: lane (la,hi) holds keys 16*s16 + 8*hi + 0..7 -> mapping cancels.
    #pragma unroll
    for (int s16 = 0; s16 < 4; ++s16) {
      const bf16x8 pb = *reinterpret_cast<const bf16x8*>(
          pw + (la << 7) + (((s16 * 32) + (hi * 16)) ^ swzP));
      o[0] = __builtin_amdgcn_mfma_f32_32x32x16_bf16(vf[s16][0], pb, o[0], 0, 0, 0);
      o[1] = __builtin_amdgcn_mfma_f32_32x32x16_bf16(vf[s16][1], pb, o[1], 0, 0, 0);
    }

    __syncthreads();   // staged K tile kt+1 visible; everyone done with klds[cur]
  }

  // epilogue: reduce lsum once (4 lanes per q over lg), normalize, packed stores.
  // D layout (32x32): row = d = dt*32 + (reg&3) + 8*(reg>>2) + 4*hi, col = q = la.
  float t0 = lsum[0]; t0 += __shfl_xor(t0, 16); t0 += __shfl_xor(t0, 32);
  float t1 = lsum[1]; t1 += __shfl_xor(t1, 16); t1 += __shfl_xor(t1, 32);
  const float inv = 1.f / (la < 16 ? t0 : t1);
  const size_t rowoff = (size_t)(b * 2048 + q0 + la) * 1024 + h * 64 + hi * 4;
  #pragma unroll
  for (int dt = 0; dt < 2; ++dt) {
    #pragma unroll
    for (int r2 = 0; r2 < 4; ++r2) {
      u32x2 w;
      w[0] = cvt_pk_bf16(o[dt][r2 * 4 + 0] * inv, o[dt][r2 * 4 + 1] * inv);
      w[1] = cvt_pk_bf16(o[dt][r2 * 4 + 2] * inv, o[dt][r2 * 4 + 3] * inv);
      *(u32x2*)(Ao + rowoff + dt * 32 + r2 * 8) = w;
    }
  }
}

// ---------------- launch ----------------
extern "C" void kernel_launch(void* const* d_in, const int* in_sizes, int n_in,
                              void* d_out, int out_size, void* d_ws, size_t ws_size,
                              hipStream_t stream) {
  const float* x  = (const float*)d_in[0];
  const float* Wq = (const float*)d_in[1];
  const float* bq = (const float*)d_in[2];
  const float* Wk = (const float*)d_in[3];
  const float* bk = (const float*)d_in[4];
  const float* Wv = (const float*)d_in[5];
  const float* bv = (const float*)d_in[6];
  const float* Wo = (const float*)d_in[7];
  const float* bo = (const float*)d_in[8];
  float* out = (float*)d_out;

  char* ws = (char*)d_ws;
  size_t off = 0;
  auto alloc = [&](size_t bytes) -> void* {
    void* p = ws + off;
    off += (bytes + 255) & ~(size_t)255;
    return p;
  };
  unsigned short* xb    = (unsigned short*)alloc((size_t)8192 * 1024 * 2); // x bf16
  unsigned short* wqkvt = (unsigned short*)alloc((size_t)1152 * 1024 * 2); // [Wq;Wk;Wv]^T bf16
  unsigned short* wot   = (unsigned short*)alloc((size_t)1024 * 1024 * 2); // Wo^T bf16
  unsigned short* qb    = (unsigned short*)alloc((size_t)8192 * 1024 * 2); // Q (b,h,n,d) scaled
  unsigned short* kb    = (unsigned short*)alloc((size_t)8192 * 64 * 2);   // K (b,n,d)
  unsigned short* vt    = (unsigned short*)alloc((size_t)4 * 64 * 2048 * 2); // V^T (b,d,n)
  unsigned short* ao    = (unsigned short*)alloc((size_t)8192 * 1024 * 2); // attn out (b,n,1024)

  cvt_x_kernel<<<8192, 256, 0, stream>>>(x, xb, 8192 * 1024 / 4);
  cvt_wt_kernel<<<dim3(32, 32), 256, 0, stream>>>(Wq, wqkvt, 1024, 1024);
  cvt_wt_kernel<<<dim3(2, 32), 256, 0, stream>>>(Wk, wqkvt + (size_t)1024 * 1024, 64, 1024);
  cvt_wt_kernel<<<dim3(2, 32), 256, 0, stream>>>(Wv, wqkvt + (size_t)1088 * 1024, 64, 1024);
  cvt_wt_kernel<<<dim3(32, 32), 256, 0, stream>>>(Wo, wot, 1024, 1024);

  gemm_kernel<0><<<dim3(64, 9), 256, 0, stream>>>(xb, wqkvt, bq, bk, bv, qb, kb, vt, 1024, 1152);
  attn_kernel<<<dim3(8, 64), 512, 0, stream>>>(qb, kb, vt, ao);
  gemm_kernel<2><<<dim3(64, 8), 256, 0, stream>>>(ao, wot, bo, nullptr, nullptr, out, nullptr, nullptr, 1024, 1024);
}

// Round 7
// 160.829 us; speedup vs baseline: 1.5521x; 1.5521x over previous
//
#include <hip/hip_runtime.h>

using bf16x8 = __attribute__((ext_vector_type(8))) short;
using f32x4  = __attribute__((ext_vector_type(4))) float;
using f32x16 = __attribute__((ext_vector_type(16))) float;
using u32x2  = __attribute__((ext_vector_type(2))) unsigned int;
using u32x4  = __attribute__((ext_vector_type(4))) unsigned int;

__device__ __forceinline__ unsigned short f2bf(float f) {
  unsigned int u = __float_as_uint(f);
  u = u + 0x7fffu + ((u >> 16) & 1u);   // round-to-nearest-even
  return (unsigned short)(u >> 16);
}

#if __has_builtin(__builtin_amdgcn_exp2f)
#define EXP2(x) __builtin_amdgcn_exp2f(x)
#else
#define EXP2(x) __expf((x) * 0.69314718056f)
#endif

// v_cvt_pk_bf16_f32: pack 2 f32 -> 2 bf16 (RTNE) in one instruction [T12]
__device__ __forceinline__ unsigned int cvt_pk_bf16(float lo, float hi) {
  unsigned int r;
  asm("v_cvt_pk_bf16_f32 %0, %1, %2" : "=v"(r) : "v"(lo), "v"(hi));
  return r;
}

#define GLL16(SRC, DST) __builtin_amdgcn_global_load_lds( \
    (const __attribute__((address_space(1))) unsigned int*)(SRC), \
    (__attribute__((address_space(3))) unsigned int*)(DST), 16, 0, 0)

// ---------------- converts ----------------
__global__ void cvt_x_kernel(const float* __restrict__ x, unsigned short* __restrict__ xb, int n4) {
  int i = blockIdx.x * blockDim.x + threadIdx.x;
  if (i >= n4) return;
  const float4 v = reinterpret_cast<const float4*>(x)[i];
  ushort2 o0 = { f2bf(v.x), f2bf(v.y) };
  ushort2 o1 = { f2bf(v.z), f2bf(v.w) };
  reinterpret_cast<ushort2*>(xb)[2 * i]     = o0;
  reinterpret_cast<ushort2*>(xb)[2 * i + 1] = o1;
}

// W (K x N) f32 row-major -> Wt (N x K) bf16 row-major. LDS-tiled, coalesced both sides.
__global__ __launch_bounds__(256) void cvt_wt_kernel(
    const float* __restrict__ W, unsigned short* __restrict__ Wt, int N, int K) {
  __shared__ float tile[32][33];
  const int n0 = blockIdx.x * 32, k0 = blockIdx.y * 32;
  const int tx = threadIdx.x & 31, ty = threadIdx.x >> 5;
  #pragma unroll
  for (int i = 0; i < 32; i += 8)
    tile[ty + i][tx] = W[(size_t)(k0 + ty + i) * N + n0 + tx];
  __syncthreads();
  #pragma unroll
  for (int i = 0; i < 32; i += 8)
    Wt[(size_t)(n0 + ty + i) * K + k0 + tx] = f2bf(tile[tx][ty + i]);
}

// ---------------- GEMM (m97 structure): C = A(M x K) @ Bt^T + bias ----------------
// MODE 0: fused QKV. N=1152. col<1024 -> Q bf16 (b,h,n,d) scaled by 0.125*log2e;
//         col in [1024,1088) -> K (b*n,64); col >= 1088 -> V^T (b,d,n) with the
//         key index bit2<->bit3 swapped within each 16-group (PV positional layout).
// MODE 2: out0 = fp32 row-major (M x N).
template<int MODE>
__global__ __launch_bounds__(256) void gemm_kernel(
    const unsigned short* __restrict__ A, const unsigned short* __restrict__ Bt,
    const float* __restrict__ bias0, const float* __restrict__ bias1,
    const float* __restrict__ bias2,
    void* __restrict__ out0, void* __restrict__ out1, void* __restrict__ out2,
    int K, int N) {
  __shared__ __align__(16) unsigned short alds[2][128 * 32];
  __shared__ __align__(16) unsigned short blds[2][128 * 32];

  const int t    = threadIdx.x;
  const int lane = t & 63;
  const int wid  = t >> 6;
  const int lr = lane & 15, lg = lane >> 4;
  const int row0 = blockIdx.x * 128;
  const int col0 = blockIdx.y * 128;

  const size_t ldb = (size_t)K * 2;
  const char* Ag = (const char*)A  + (size_t)(row0 + (t >> 2)) * ldb + ((t & 3) << 4);
  const char* Bg = (const char*)Bt + (size_t)(col0 + (t >> 2)) * ldb + ((t & 3) << 4);
  char* adst = (char*)alds[0] + wid * 1024;
  char* bdst = (char*)blds[0] + wid * 1024;

  auto stage = [&](int buf, int k0) {
    const size_t kb = (size_t)k0 * 2;
    #pragma unroll
    for (int c = 0; c < 2; ++c) {
      GLL16(Ag + (size_t)c * 64 * ldb + kb, adst + buf * 8192 + c * 4096);
      GLL16(Bg + (size_t)c * 64 * ldb + kb, bdst + buf * 8192 + c * 4096);
    }
  };

  f32x4 acc[4][4];
  #pragma unroll
  for (int i = 0; i < 4; ++i)
    #pragma unroll
    for (int j = 0; j < 4; ++j)
      #pragma unroll
      for (int r = 0; r < 4; ++r) acc[i][j][r] = 0.f;

  stage(0, 0);
  __syncthreads();

  for (int step = 0; step < 32; ++step) {
    const int cur = step & 1;
    if (step < 31) stage(cur ^ 1, (step + 1) * 32);

    const char* ab = (const char*)alds[cur] + (wid >> 1) * 4096;
    const char* bb = (const char*)blds[cur] + (wid & 1) * 4096;
    bf16x8 am[4], bn[4];
    #pragma unroll
    for (int i = 0; i < 4; ++i)
      am[i] = *reinterpret_cast<const bf16x8*>(ab + (i * 16 + lr) * 64 + lg * 16);
    #pragma unroll
    for (int j = 0; j < 4; ++j)
      bn[j] = *reinterpret_cast<const bf16x8*>(bb + (j * 16 + lr) * 64 + lg * 16);
    #pragma unroll
    for (int i = 0; i < 4; ++i)
      #pragma unroll
      for (int j = 0; j < 4; ++j)
        acc[i][j] = __builtin_amdgcn_mfma_f32_16x16x32_bf16(am[i], bn[j], acc[i][j], 0, 0, 0);

    __syncthreads();
  }

  const int wrow0 = row0 + (wid >> 1) * 64;
  const int wcol0 = col0 + (wid & 1) * 64;
  #pragma unroll
  for (int i = 0; i < 4; ++i) {
    #pragma unroll
    for (int j = 0; j < 4; ++j) {
      const int col = wcol0 + j * 16 + lr;
      float bias;
      if constexpr (MODE == 0)
        bias = (col < 1024) ? bias0[col] : ((col < 1088) ? bias1[col - 1024] : bias2[col - 1088]);
      else
        bias = bias0[col];
      #pragma unroll
      for (int r = 0; r < 4; ++r) {
        const int row = wrow0 + i * 16 + lg * 4 + r;
        float v = acc[i][j][r] + bias;
        if constexpr (MODE == 0) {
          const int b = row >> 11, n = row & 2047;
          if (col < 1024) {
            v *= 0.180336880111f;  // 0.125 * log2(e): softmax scale + exp2 domain
            const int h = col >> 6, d = col & 63;
            ((unsigned short*)out0)[(((b * 16 + h) * 2048) + n) * 64 + d] = f2bf(v);
          } else if (col < 1088) {
            ((unsigned short*)out1)[row * 64 + (col - 1024)] = f2bf(v);      // K: (b*2048+n, d)
          } else {
            // V^T (b, d, n'), n' = bit2<->bit3 swap within each 16-key group
            const int np = (n & ~15) | (n & 3) | ((n & 4) << 1) | ((n & 8) >> 1);
            ((unsigned short*)out2)[(b * 64 + (col - 1088)) * 2048 + np] = f2bf(v);
          }
        } else {
          ((float*)out0)[(size_t)row * N + col] = v;
        }
      }
    }
  }
}

// ---------------- attention (32x32 MFMA, P fully in-register, no P-LDS) ----------------
// 8 waves x 32 q-rows, grid (8, 64). K and V staged in LDS (global_load_lds, dbuf,
// XOR-swizzled). QK^T swapped: S^T = mfma32(K, Q), both operands positional (same
// d-enumeration) -> cancellation-safe. S^T D-layout (verified m74/m101): col=q=la,
// row=key=(r&3)+8*(r>>2)+4*hi. So lane's own cvt_pk words ARE the PV B-frag for
// enumeration e(w,hi) = {16ks+4hi+0..3, 16ks+8+4hi+0..3}; V^T is stored with that
// same key permutation (bit2<->bit3 in n&15), so vf is a single positional b128 read.
// No cross-lane ops in the loop; lsum reduced once in the epilogue. No max
// subtraction (scores pre-scaled by 0.125*log2e, bounded). T5 setprio around MFMA.
__global__ __launch_bounds__(512, 4) void attn_kernel(
    const unsigned short* __restrict__ Q,   // (bh, n, 64), pre-scaled by 0.125*log2e
    const unsigned short* __restrict__ Kb,  // (b, n, 64)
    const unsigned short* __restrict__ Vt,  // (b, 64, n-permuted)
    unsigned short* __restrict__ Ao) {      // (b, n, 1024)
  __shared__ __align__(16) unsigned short klds[2][64 * 64];   // 16 KB
  __shared__ __align__(16) unsigned short vlds[2][64 * 64];   // 16 KB

  const int lane = threadIdx.x & 63;
  const int wid  = threadIdx.x >> 6;
  const int la = lane & 31, hi = lane >> 5;
  const int swz = (la & 7) << 4;            // read swizzle (row&7 == la&7 for all reads)
  const int bh = blockIdx.y, b = bh >> 4, h = bh & 15;
  const int q0 = blockIdx.x * 256 + wid * 32;

  const unsigned short* Qb = Q + (size_t)bh * 2048 * 64;
  const char* Kbase = (const char*)(Kb + (size_t)b * 2048 * 64);
  const char* Vbase = (const char*)(Vt + (size_t)b * 64 * 2048);

  // staging: wave w stages rows w*8..w*8+7 of the 64-row tile (1 KB per gload_lds)
  const int srow  = lane >> 3;
  const int schnk = (lane & 7) ^ (srow & 7);        // pre-swizzled source chunk
  const int krow  = wid * 8 + srow;
  const int koff_lane = krow * 128  + schnk * 16;   // K: row stride 128B
  const int voff_lane = krow * 4096 + schnk * 16;   // Vt: row stride 4096B
  char* kdst = (char*)klds[0] + wid * 1024;
  char* vdst = (char*)vlds[0] + wid * 1024;

  auto stage = [&](int buf, int kt) {
    GLL16(Kbase + (size_t)kt * 8192 + koff_lane, kdst + buf * 8192);
    GLL16(Vbase + (size_t)kt * 128  + voff_lane, vdst + buf * 8192);
  };

  // Q B-frags (loop-invariant), positional: col=q=q0+la, d = kc*16 + hi*8 + j
  bf16x8 qa[4];
  #pragma unroll
  for (int kc = 0; kc < 4; ++kc)
    qa[kc] = *reinterpret_cast<const bf16x8*>(&Qb[(q0 + la) * 64 + kc * 16 + hi * 8]);

  float lsum = 0.f;
  f32x16 o[2];
  #pragma unroll
  for (int dt = 0; dt < 2; ++dt)
    #pragma unroll
    for (int r = 0; r < 16; ++r) o[dt][r] = 0.f;

  stage(0, 0);
  __syncthreads();

  for (int kt = 0; kt < 32; ++kt) {
    const int cur = kt & 1;
    if (kt < 31) stage(cur ^ 1, kt + 1);   // prefetch next K/V tile

    const char* kb8 = (const char*)klds[cur];
    const char* vb8 = (const char*)vlds[cur];

    #pragma unroll
    for (int ct = 0; ct < 2; ++ct) {
      // S^T (32 keys x 32 q) = K_tile @ Q^T, positional A/B (enumeration cancels)
      f32x16 s;
      #pragma unroll
      for (int r = 0; r < 16; ++r) s[r] = 0.f;
      __builtin_amdgcn_s_setprio(1);
      #pragma unroll
      for (int kc = 0; kc < 4; ++kc) {
        const bf16x8 kf = *reinterpret_cast<const bf16x8*>(
            kb8 + ((ct * 32 + la) << 7) + ((((kc << 1) + hi) << 4) ^ swz));
        s = __builtin_amdgcn_mfma_f32_32x32x16_bf16(kf, qa[kc], s, 0, 0, 0);
      }
      __builtin_amdgcn_s_setprio(0);

      // P = exp2(S); pack to bf16 pairs. Register r = 4*r2+q holds key 8*r2+4*hi+q
      // (verified D-layout) -> W[r2][p] = keys {8r2+4hi+2p, +1}.
      unsigned int W[4][2];
      float ps = 0.f;
      #pragma unroll
      for (int r2 = 0; r2 < 4; ++r2) {
        const float p0 = EXP2(s[r2 * 4 + 0]);
        const float p1 = EXP2(s[r2 * 4 + 1]);
        const float p2 = EXP2(s[r2 * 4 + 2]);
        const float p3 = EXP2(s[r2 * 4 + 3]);
        ps += (p0 + p1) + (p2 + p3);
        W[r2][0] = cvt_pk_bf16(p0, p1);
        W[r2][1] = cvt_pk_bf16(p2, p3);
      }
      lsum += ps;

      // PV: O^T += V @ P, 2 k-steps of 16 keys. B-frag = own W words (enumeration
      // e(w,hi)); A-frag = positional b128 from permuted-V LDS (same e). f==g.
      __builtin_amdgcn_s_setprio(1);
      #pragma unroll
      for (int ks = 0; ks < 2; ++ks) {
        u32x4 pwv;
        pwv[0] = W[2 * ks][0];
        pwv[1] = W[2 * ks][1];
        pwv[2] = W[2 * ks + 1][0];
        pwv[3] = W[2 * ks + 1][1];
        const bf16x8 pb = __builtin_bit_cast(bf16x8, pwv);
        #pragma unroll
        for (int dt = 0; dt < 2; ++dt) {
          const bf16x8 vf = *reinterpret_cast<const bf16x8*>(
              vb8 + ((dt * 32 + la) << 7) + (((((ct * 2 + ks) << 1) + hi) << 4) ^ swz));
          o[dt] = __builtin_amdgcn_mfma_f32_32x32x16_bf16(vf, pb, o[dt], 0, 0, 0);
        }
      }
      __builtin_amdgcn_s_setprio(0);
    }

    __syncthreads();   // staged tile kt+1 visible; everyone done with buf[cur]
  }

  // epilogue: one cross-half reduce, normalize, packed 8B stores.
  // D layout (32x32): row = d = dt*32 + (r&3) + 8*(r>>2) + 4*hi, col = q = la.
  lsum += __shfl_xor(lsum, 32);
  const float inv = 1.f / lsum;
  const size_t rowoff = (size_t)(b * 2048 + q0 + la) * 1024 + h * 64 + hi * 4;
  #pragma unroll
  for (int dt = 0; dt < 2; ++dt) {
    #pragma unroll
    for (int r2 = 0; r2 < 4; ++r2) {
      u32x2 w;
      w[0] = cvt_pk_bf16(o[dt][r2 * 4 + 0] * inv, o[dt][r2 * 4 + 1] * inv);
      w[1] = cvt_pk_bf16(o[dt][r2 * 4 + 2] * inv, o[dt][r2 * 4 + 3] * inv);
      *(u32x2*)(Ao + rowoff + dt * 32 + r2 * 8) = w;
    }
  }
}

// ---------------- launch ----------------
extern "C" void kernel_launch(void* const* d_in, const int* in_sizes, int n_in,
                              void* d_out, int out_size, void* d_ws, size_t ws_size,
                              hipStream_t stream) {
  const float* x  = (const float*)d_in[0];
  const float* Wq = (const float*)d_in[1];
  const float* bq = (const float*)d_in[2];
  const float* Wk = (const float*)d_in[3];
  const float* bk = (const float*)d_in[4];
  const float* Wv = (const float*)d_in[5];
  const float* bv = (const float*)d_in[6];
  const float* Wo = (const float*)d_in[7];
  const float* bo = (const float*)d_in[8];
  float* out = (float*)d_out;

  char* ws = (char*)d_ws;
  size_t off = 0;
  auto alloc = [&](size_t bytes) -> void* {
    void* p = ws + off;
    off += (bytes + 255) & ~(size_t)255;
    return p;
  };
  unsigned short* xb    = (unsigned short*)alloc((size_t)8192 * 1024 * 2); // x bf16
  unsigned short* wqkvt = (unsigned short*)alloc((size_t)1152 * 1024 * 2); // [Wq;Wk;Wv]^T bf16
  unsigned short* wot   = (unsigned short*)alloc((size_t)1024 * 1024 * 2); // Wo^T bf16
  unsigned short* qb    = (unsigned short*)alloc((size_t)8192 * 1024 * 2); // Q (b,h,n,d) scaled
  unsigned short* kb    = (unsigned short*)alloc((size_t)8192 * 64 * 2);   // K (b,n,d)
  unsigned short* vt    = (unsigned short*)alloc((size_t)4 * 64 * 2048 * 2); // V^T permuted
  unsigned short* ao    = (unsigned short*)alloc((size_t)8192 * 1024 * 2); // attn out (b,n,1024)

  cvt_x_kernel<<<8192, 256, 0, stream>>>(x, xb, 8192 * 1024 / 4);
  cvt_wt_kernel<<<dim3(32, 32), 256, 0, stream>>>(Wq, wqkvt, 1024, 1024);
  cvt_wt_kernel<<<dim3(2, 32), 256, 0, stream>>>(Wk, wqkvt + (size_t)1024 * 1024, 64, 1024);
  cvt_wt_kernel<<<dim3(2, 32), 256, 0, stream>>>(Wv, wqkvt + (size_t)1088 * 1024, 64, 1024);
  cvt_wt_kernel<<<dim3(32, 32), 256, 0, stream>>>(Wo, wot, 1024, 1024);

  gemm_kernel<0><<<dim3(64, 9), 256, 0, stream>>>(xb, wqkvt, bq, bk, bv, qb, kb, vt, 1024, 1152);
  attn_kernel<<<dim3(8, 64), 512, 0, stream>>>(qb, kb, vt, ao);
  gemm_kernel<2><<<dim3(64, 8), 256, 0, stream>>>(ao, wot, bo, nullptr, nullptr, out, nullptr, nullptr, 1024, 1024);
}